// Round 9
// baseline (1171.093 us; speedup 1.0000x reference)
//
#include <hip/hip_runtime.h>
#include <cstdint>

typedef unsigned long long u64;
typedef unsigned int u32;

#define B_ 4
#define N_ 3600
#define C_ 16
#define RPW_ 4        // rows per wave (k_iou)
#define RPB_ 16       // rows per block (k_iou, 4 waves)
#define HW0_ 1856     // j-half 0: words 0..28  (29 words)
#define HW1_ 1792     // j-half 1: words 29..56 (28 words)
#define NW_ 57        // words per N-row
#define NPAD_ 3648
#define CH_ 64        // greedy chunk size
#define TMAX_ 512     // fast-path candidate cap (T~330 measured)
#define TWMX_ 8       // TMAX_/64
#define CPAD_ 9       // cmat row pad
#define NT_ 1024      // threads in nms kernels (16 waves -> 4/SIMD)
#define NWV_ 16
#define NSEQW_ 114    // ceil(NPAD_/32) u32 valid words (k_seq)

// Order-preserving float->u32 transform (total order; data has no -0.0/NaN,
// so numeric-compare semantics match reference float >=).
__device__ __forceinline__ u32 xf32(float f) {
    const u32 b = __float_as_uint(f);
    return b ^ ((b >> 31) ? 0xFFFFFFFFu : 0x80000000u);
}

// ---------------------------------------------------------------------------
// K0: seed thr[i][c] = xf32(con[i][c]) (so final thr = max(con_i, adj_con)
// exactly: p>=a && p>=b <=> p>=max(a,b) for non-NaN) + zero candidate cnts.
// ---------------------------------------------------------------------------
__global__ __launch_bounds__(512) void k_init(const float* __restrict__ con,
                                              u32* __restrict__ thr,
                                              u32* __restrict__ cnt) {
    const int x = blockIdx.x * 512 + threadIdx.x;
    if (x < B_ * N_ * C_) thr[x] = xf32(con[x]);
    if (blockIdx.x == 0)
        for (int y = threadIdx.x; y < B_ * C_ * 16; y += 512) cnt[y] = 0;
}

// ---------------------------------------------------------------------------
// K1 (k_iou): upper-triangle IoU pairs (j > i), LDS-staged j-range (proven
// R2/R4 structure). NO adjacency matrix: on each (rare, ~9/3600) hit, scatter
// atomicMax(xf32(con)) into thr for BOTH endpoints — replaces the old
// adj-store + k_tr bit-transpose + k_acon gather pipeline entirely.
// Exact division-free IoU: round_f32(inter/denom) >= 0.4f  <=>
// inter > (0.4f - 2^-26)*denom in f64 (26x24-bit product exact; midpoint
// ties round-to-even below 0.4f -> false, matching strict '>'; denom==0 =>
// inter==0 => false = reference NaN>=0.4). j>i excludes diagonal; padding
// boxes (j>=N) are zeroed -> pred false -> no OOB access.
// ---------------------------------------------------------------------------
__global__ __launch_bounds__(256, 4) void k_iou(const float* __restrict__ boxes,
                                                const float* __restrict__ con,
                                                u32* __restrict__ thr) {
#pragma clang fp contract(off)
    __shared__ float4 sbox[HW0_];
    const int tid  = threadIdx.x;
    const int lane = tid & 63;
    const int wv   = tid >> 6;
    const int g    = blockIdx.x;                 // 0 .. B*N/16-1
    const int b    = g / (N_ / RPB_);
    const int rg   = g % (N_ / RPB_);
    const int r0   = rg * RPB_ + wv * RPW_;
    const int w0   = rg >> 2;                    // first word (block-uniform)
    const size_t bN = (size_t)b * N_;

    float4 bi[RPW_];
    float  ai[RPW_];
#pragma unroll
    for (int r = 0; r < RPW_; ++r) {
        const float4 bx = reinterpret_cast<const float4*>(boxes)[bN + r0 + r];
        const float x1 = bx.x - bx.z * 0.5f;   // reference op order
        const float y1 = bx.y - bx.w * 0.5f;
        const float x2 = x1 + bx.z;
        const float y2 = y1 + bx.w;
        bi[r] = make_float4(x1, y1, x2, y2);
        ai[r] = (x2 - x1) * (y2 - y1);
    }
    const double MID = (double)0.4f - 0x1p-26;   // exact

    int jbase = 0;
    for (int h = 0; h < 2; ++h) {
        const int cnt_h = h ? HW1_ : HW0_;
        const int wlo   = jbase >> 6;
        const int wcnt  = cnt_h >> 6;
        if (w0 < wlo + wcnt) {                   // block-uniform skip
            const int tw0 = max(w0 - wlo, 0);
            const int jj0 = tw0 << 6;
            __syncthreads();
            for (int jj = jj0 + tid; jj < cnt_h; jj += 256) {
                const int j = jbase + jj;
                float x1 = 0.f, y1 = 0.f, x2 = 0.f, y2 = 0.f;
                if (j < N_) {
                    const float4 bx = reinterpret_cast<const float4*>(boxes)[bN + j];
                    x1 = bx.x - bx.z * 0.5f;
                    y1 = bx.y - bx.w * 0.5f;
                    x2 = x1 + bx.z;
                    y2 = y1 + bx.w;
                }
                sbox[jj] = make_float4(x1, y1, x2, y2);
            }
            __syncthreads();

            for (int tw = tw0; tw < wcnt; ++tw) {
                const int j = jbase + tw * 64 + lane;
                const float4 bj = sbox[tw * 64 + lane];
                const float ajr = (bj.z - bj.x) * (bj.w - bj.y);
#pragma unroll
                for (int r = 0; r < RPW_; ++r) {
                    const int i = r0 + r;
                    const float ltx = fmaxf(bi[r].x, bj.x);
                    const float lty = fmaxf(bi[r].y, bj.y);
                    const float rbx = fminf(bi[r].z, bj.z);
                    const float rby = fminf(bi[r].w, bj.w);
                    const float whx = fmaxf(rbx - ltx, 0.0f);
                    const float why = fmaxf(rby - lty, 0.0f);
                    const float inter = whx * why;
                    const float denom = (ai[r] + ajr) - inter;
                    const bool pred = ((double)inter > MID * (double)denom)
                                      && (j > i);
                    if (pred) {                  // rare (~0.25%): dual scatter
                        const float4* ci4 =
                            reinterpret_cast<const float4*>(con + (bN + i) * C_);
                        const float4* cj4 =
                            reinterpret_cast<const float4*>(con + (bN + j) * C_);
                        u32* ti = thr + (bN + i) * C_;
                        u32* tj = thr + (bN + j) * C_;
#pragma unroll
                        for (int q = 0; q < 4; ++q) {
                            const float4 vj = cj4[q];
                            const float4 vi = ci4[q];
                            atomicMax(&ti[q * 4 + 0], xf32(vj.x));
                            atomicMax(&ti[q * 4 + 1], xf32(vj.y));
                            atomicMax(&ti[q * 4 + 2], xf32(vj.z));
                            atomicMax(&ti[q * 4 + 3], xf32(vj.w));
                            atomicMax(&tj[q * 4 + 0], xf32(vi.x));
                            atomicMax(&tj[q * 4 + 1], xf32(vi.y));
                            atomicMax(&tj[q * 4 + 2], xf32(vi.z));
                            atomicMax(&tj[q * 4 + 3], xf32(vi.w));
                        }
                    }
                }
            }
        }
        jbase += cnt_h;
    }
}

// ---------------------------------------------------------------------------
// K2 (k_valid): elementwise candidate emission. valid0 = (p >= conf_c) &&
// (xf32(p) >= thr) — thr already holds xf32(max(con_i, adj_con)); transform
// is order-preserving so compares match reference. Key (~xf32(p))<<32 | i;
// arrival order nondeterministic, keys unique -> sort canonicalizes.
// ---------------------------------------------------------------------------
__global__ __launch_bounds__(512) void k_valid(const float* __restrict__ pro,
                                               const u32* __restrict__ thr,
                                               const float* __restrict__ conf,
                                               u64* __restrict__ cand,
                                               u32* __restrict__ cnt) {
    const int x = blockIdx.x * 512 + threadIdx.x;  // ((b*N + i)*C + c)
    if (x >= B_ * N_ * C_) return;
    const int c  = x & (C_ - 1);
    const int bi = x >> 4;
    const int b  = bi / N_;
    const int i  = bi % N_;
    const float p = pro[x];
    if (p >= conf[c]) {
        const u32 pt = xf32(p);
        if (pt >= thr[x]) {
            const u32 pos = atomicAdd(&cnt[(b * C_ + c) * 16], 1u);
            cand[(size_t)(b * C_ + c) * N_ + pos] =
                (((u64)(~pt)) << 32) | (u32)i;
        }
    }
}

// ---------------------------------------------------------------------------
// K3 FAST PATH (T <= TMAX_): candidate-space NMS, 1024 threads (16 waves ->
// 4/SIMD for latency cover). cmat built by direct IoU recomputation, UPPER-
// TRIANGLE WORDS ONLY (g >= r>>6): the greedy never reads lower words (peel
// uses the diagonal word, built full; suppression only words g > ch). Halves
// R8's build. Sort gated to waves covering T. Garbage in pad rows/cols is
// masked by cn/cv everywhere. Full-slice output (absorbs memset).
// Exactness: IoU FP sequence identical to k_iou; peel == sequential greedy
// (R6/R7-proven: round-accept candidates with no earlier UNDECIDED neighbor).
// ---------------------------------------------------------------------------
__global__ __launch_bounds__(NT_) void k_nms_fast(const u64* __restrict__ cand,
                                                  const u32* __restrict__ cnt,
                                                  const float* __restrict__ boxes,
                                                  const float* __restrict__ scales,
                                                  float* __restrict__ out) {
#pragma clang fp contract(off)
    __shared__ union {
        u64 keys[TMAX_];                 // 4 KB   (live: sort)
        u64 cmat[TMAX_][CPAD_];          // 36.9 KB (live: build/greedy)
    } ov;
    __shared__ float4 cbox[TMAX_];
    __shared__ u32 sidx[TMAX_];
    __shared__ float sscore[TMAX_];
    __shared__ u32 slist[TMAX_];
    __shared__ float slistf[TMAX_];
    __shared__ u64 valid[TWMX_];
    __shared__ u64 s_accept;
    __shared__ u32 s_S;
    const int tid  = threadIdx.x;
    const int lane = tid & 63;
    const int wv   = tid >> 6;
    const int bc   = blockIdx.x;
    const int b    = bc / C_;
    const size_t bN = (size_t)b * N_;
    const double MID = (double)0.4f - 0x1p-26;

    const int T = (int)cnt[bc * 16];
    if (T > TMAX_) return;                       // k_seq handles
    const int TW = (T + 63) >> 6;

    for (int x = tid; x < TW * 64; x += NT_)
        ov.keys[x] = (x < T) ? cand[(size_t)bc * N_ + x] : ~0ull;
    if (tid < TWMX_) valid[tid] = ~0ull;
    __syncthreads();

    // --- sort: readlane rank, gated to participating waves ---
    if (tid < TW * 64) {
        const u64 kx = ov.keys[tid];
        u32 rank = 0;
        for (int yb = 0; yb < TW; ++yb) {
            const u64 ky = ov.keys[yb * 64 + lane];
            const u32 kyl = (u32)ky, kyh = (u32)(ky >> 32);
#pragma unroll
            for (int l = 0; l < 64; ++l) {
                const u64 kb =
                    ((u64)(u32)__builtin_amdgcn_readlane((int)kyh, l) << 32)
                  |  (u64)(u32)__builtin_amdgcn_readlane((int)kyl, l);
                rank += (kb < kx) ? 1u : 0u;
            }
        }
        if (tid < T) {
            sidx[rank] = (u32)(kx & 0xFFFFFFFFull);
            const u32 pk = ~((u32)(kx >> 32));
            const u32 pb = (pk & 0x80000000u) ? (pk ^ 0x80000000u) : ~pk;
            sscore[rank] = __uint_as_float(pb);
        }
    }
    for (int x = tid; x < TW * 64; x += NT_)
        if (x >= T) sidx[x] = 0u;                // pad (disjoint from ranks)
    __syncthreads();

    // --- stage candidate boxes (op order == k_iou -> bit-identical) ---
    for (int t = tid; t < TW * 64; t += NT_) {
        const u32 idx = sidx[t];
        const float4 bx = reinterpret_cast<const float4*>(boxes)[bN + idx];
        const float x1 = bx.x - bx.z * 0.5f;
        const float y1 = bx.y - bx.w * 0.5f;
        const float x2 = x1 + bx.z;
        const float y2 = y1 + bx.w;
        cbox[t] = make_float4(x1, y1, x2, y2);
    }
    __syncthreads();                     // keys dead; cmat may overlay now

    // --- build cmat, upper-triangle words only ---
    for (int r = wv; r < T; r += NWV_) {
        const float4 bi = cbox[r];
        const float ai = (bi.z - bi.x) * (bi.w - bi.y);
        for (int gg = r >> 6; gg < TW; ++gg) {
            const float4 bj = cbox[gg * 64 + lane];
            const float ajr = (bj.z - bj.x) * (bj.w - bj.y);
            const float ltx = fmaxf(bi.x, bj.x);
            const float lty = fmaxf(bi.y, bj.y);
            const float rbx = fminf(bi.z, bj.z);
            const float rby = fminf(bi.w, bj.w);
            const float whx = fmaxf(rbx - ltx, 0.0f);
            const float why = fmaxf(rby - lty, 0.0f);
            const float inter = whx * why;
            const float denom = (ai + ajr) - inter;
            const int pred = ((double)inter > MID * (double)denom) &&
                             (gg * 64 + lane != r);
            const u64 bm = __ballot(pred);
            if (lane == 0) ov.cmat[r][gg] = bm;
        }
    }
    __syncthreads();

    // --- chunked greedy in candidate space ---
    u32 S = 0;                           // meaningful in wave 0
    const int NCH = (T + CH_ - 1) / CH_;
    for (int ch = 0; ch < NCH; ++ch) {
        const int c0 = ch * CH_;
        const int cn = min(CH_, T - c0);

        if (wv == 0) {                   // peel == sequential greedy
            const u64 cmask = (cn >= 64) ? ~0ull : ((1ull << cn) - 1ull);
            u64 cv = valid[ch] & cmask;
            const u64 iv = (lane < cn) ? ov.cmat[c0 + lane][ch] : 0ull;
            const u64 below = (1ull << lane) - 1ull;
            u64 accept = 0ull;
            while (cv) {
                const int ok = ((cv >> lane) & 1ull) &&
                               ((iv & below & cv) == 0ull);
                const u64 ar = __ballot(ok);
                u64 sup = ok ? iv : 0ull;
#pragma unroll
                for (int off = 1; off < 64; off <<= 1)
                    sup |= __shfl_xor(sup, off);
                accept |= ar;
                cv &= ~(ar | sup);
            }
            if (lane == 0) s_accept = accept;
            if ((accept >> lane) & 1ull) {
                const u32 pos = S + (u32)__popcll(accept & below);
                slist[pos]  = sidx[c0 + lane];
                slistf[pos] = sscore[c0 + lane];
            }
            S += (u32)__popcll(accept);
        }
        __syncthreads();

        const u64 ac = s_accept;         // suppress later words (1 wave/word)
        const int gg = ch + 1 + wv;
        if (gg < TW && ac) {
            u64 sup = ((ac >> lane) & 1ull) ? ov.cmat[c0 + lane][gg] : 0ull;
#pragma unroll
            for (int off = 1; off < 64; off <<= 1)
                sup |= __shfl_xor(sup, off);
            if (lane == 0) valid[gg] &= ~sup;
        }
        __syncthreads();
    }
    if (wv == 0 && lane == 0) s_S = S;
    __syncthreads();

    // --- full-slice output (zeros past Sf) ---
    const int Sf = (int)s_S;
    const float s = scales[b];
    for (int r = tid; r < N_; r += NT_) {
        float o0 = 0.f, o1 = 0.f, o2 = 0.f, o3 = 0.f, o4 = 0.f, mk = 0.f;
        if (r < Sf) {
            const int idx = (int)slist[r];
            const float4 bx = reinterpret_cast<const float4*>(boxes)[bN + idx];
            const float scx = bx.x * s, scy = bx.y * s;
            const float sw  = bx.z * s, sh  = bx.w * s;
            o0 = scx - 0.5f * sw;
            o1 = scy - 0.5f * sh;
            o2 = scx + 0.5f * sw;
            o3 = scy + 0.5f * sh;
            o4 = slistf[r];
            mk = 1.0f;
        }
        float* o = out + ((size_t)bc * N_ + r) * 5;
        o[0] = o0; o[1] = o1; o[2] = o2; o[3] = o3; o[4] = o4;
        out[(size_t)B_ * C_ * N_ * 5 + (size_t)bc * N_ + r] = mk;
    }
}

// ---------------------------------------------------------------------------
// K4 SLOW PATH (T > TMAX_ only — never on this data; correctness insurance
// without the adj matrix): sort, stage all candidate boxes in LDS, then
// simple sequential greedy with on-the-fly IoU suppression (parallel over
// later candidates). Output rows written at accept time; zeros filled after.
// ---------------------------------------------------------------------------
__global__ __launch_bounds__(NT_) void k_seq(const u64* __restrict__ cand,
                                             const u32* __restrict__ cnt,
                                             const float* __restrict__ boxes,
                                             const float* __restrict__ scales,
                                             float* __restrict__ out) {
#pragma clang fp contract(off)
    __shared__ union {
        u64 keys[NPAD_];                 // 29.2 KB (live: sort)
        float4 cboxN[NPAD_];             // 58.4 KB (live: greedy)
    } ovs;
    __shared__ u32 sidx[NPAD_];
    __shared__ float sscore[NPAD_];
    __shared__ u32 validw[NSEQW_];
    __shared__ u32 s_S;
    const int tid  = threadIdx.x;
    const int lane = tid & 63;
    const int bc   = blockIdx.x;
    const int b    = bc / C_;
    const size_t bN = (size_t)b * N_;
    const double MID = (double)0.4f - 0x1p-26;

    const int T = (int)cnt[bc * 16];
    if (T <= TMAX_) return;                      // fast path handled
    const int TW = (T + 63) >> 6;

    for (int x = tid; x < TW * 64; x += NT_)
        ovs.keys[x] = (x < T) ? cand[(size_t)bc * N_ + x] : ~0ull;
    for (int x = tid; x < NSEQW_; x += NT_) validw[x] = ~0u;
    __syncthreads();

    for (int xp = 0; xp * NT_ < TW * 64; ++xp) {
        const int x = xp * NT_ + tid;
        if (x < TW * 64) {
            const u64 kx = ovs.keys[x];
            u32 rank = 0;
            for (int yb = 0; yb < TW; ++yb) {
                const u64 ky = ovs.keys[yb * 64 + lane];
                const u32 kyl = (u32)ky, kyh = (u32)(ky >> 32);
#pragma unroll
                for (int l = 0; l < 64; ++l) {
                    const u64 kb =
                        ((u64)(u32)__builtin_amdgcn_readlane((int)kyh, l) << 32)
                      |  (u64)(u32)__builtin_amdgcn_readlane((int)kyl, l);
                    rank += (kb < kx) ? 1u : 0u;
                }
            }
            if (x < T) {
                sidx[rank] = (u32)(kx & 0xFFFFFFFFull);
                const u32 pk = ~((u32)(kx >> 32));
                const u32 pb = (pk & 0x80000000u) ? (pk ^ 0x80000000u) : ~pk;
                sscore[rank] = __uint_as_float(pb);
            }
        }
    }
    __syncthreads();                     // keys dead; cboxN may overlay

    for (int t = tid; t < T; t += NT_) {
        const u32 idx = sidx[t];
        const float4 bx = reinterpret_cast<const float4*>(boxes)[bN + idx];
        const float x1 = bx.x - bx.z * 0.5f;
        const float y1 = bx.y - bx.w * 0.5f;
        const float x2 = x1 + bx.z;
        const float y2 = y1 + bx.w;
        ovs.cboxN[t] = make_float4(x1, y1, x2, y2);
    }
    __syncthreads();

    const float s = scales[b];
    u32 S = 0;                           // meaningful in thread 0
    for (int k = 0; k < T; ++k) {
        if ((validw[k >> 5] >> (k & 31)) & 1u) {     // uniform LDS read
            const float4 bi = ovs.cboxN[k];
            const float ai = (bi.z - bi.x) * (bi.w - bi.y);
            if (tid == 0) {
                const u32 idx = sidx[k];
                const float4 bx = reinterpret_cast<const float4*>(boxes)[bN + idx];
                const float scx = bx.x * s, scy = bx.y * s;
                const float sw  = bx.z * s, sh  = bx.w * s;
                float* o = out + ((size_t)bc * N_ + S) * 5;
                o[0] = scx - 0.5f * sw;
                o[1] = scy - 0.5f * sh;
                o[2] = scx + 0.5f * sw;
                o[3] = scy + 0.5f * sh;
                o[4] = sscore[k];
                out[(size_t)B_ * C_ * N_ * 5 + (size_t)bc * N_ + S] = 1.0f;
                ++S;
            }
            for (int m = k + 1 + tid; m < T; m += NT_) {
                const float4 bj = ovs.cboxN[m];
                const float ajr = (bj.z - bj.x) * (bj.w - bj.y);
                const float ltx = fmaxf(bi.x, bj.x);
                const float lty = fmaxf(bi.y, bj.y);
                const float rbx = fminf(bi.z, bj.z);
                const float rby = fminf(bi.w, bj.w);
                const float whx = fmaxf(rbx - ltx, 0.0f);
                const float why = fmaxf(rby - lty, 0.0f);
                const float inter = whx * why;
                const float denom = (ai + ajr) - inter;
                if ((double)inter > MID * (double)denom)
                    atomicAnd(&validw[m >> 5], ~(1u << (m & 31)));
            }
            __syncthreads();
        }
    }
    if (tid == 0) s_S = S;
    __syncthreads();

    for (int r = (int)s_S + tid; r < N_; r += NT_) {
        float* o = out + ((size_t)bc * N_ + r) * 5;
        o[0] = 0.f; o[1] = 0.f; o[2] = 0.f; o[3] = 0.f; o[4] = 0.f;
        out[(size_t)B_ * C_ * N_ * 5 + (size_t)bc * N_ + r] = 0.f;
    }
}

// ---------------------------------------------------------------------------
extern "C" void kernel_launch(void* const* d_in, const int* in_sizes, int n_in,
                              void* d_out, int out_size, void* d_ws, size_t ws_size,
                              hipStream_t stream) {
    const float* pro    = (const float*)d_in[0];   // (B,N,C)
    const float* con    = (const float*)d_in[1];   // (B,N,C)
    const float* boxes  = (const float*)d_in[2];   // (B,N,4)
    const float* scales = (const float*)d_in[3];   // (B,)
    const float* conf   = (const float*)d_in[4];   // (C,)

    char* ws = (char*)d_ws;
    u32* thr  = (u32*)ws;                                  // B*N*C u32 (0.92 MB)
    size_t off = (size_t)B_ * N_ * C_ * sizeof(u32);
    u64* cand = (u64*)(ws + off);                          // B*C*N u64 (1.84 MB)
    off += (size_t)B_ * C_ * N_ * sizeof(u64);
    u32* cnt  = (u32*)(ws + off);                          // B*C*16 u32 (padded)

    k_init    <<<450,             512, 0, stream>>>(con, thr, cnt);
    k_iou     <<<B_ * N_ / RPB_,  256, 0, stream>>>(boxes, con, thr);
    k_valid   <<<450,             512, 0, stream>>>(pro, thr, conf, cand, cnt);
    k_nms_fast<<<B_ * C_,         NT_, 0, stream>>>(cand, cnt, boxes,
                                                    scales, (float*)d_out);
    k_seq     <<<B_ * C_,         NT_, 0, stream>>>(cand, cnt, boxes,
                                                    scales, (float*)d_out);
}

// Round 10
// 161.447 us; speedup vs baseline: 7.2537x; 7.2537x over previous
//
#include <hip/hip_runtime.h>
#include <cstdint>

typedef unsigned long long u64;
typedef unsigned int u32;

#define B_ 4
#define N_ 3600
#define C_ 16
#define NW_ 57        // ceil(N/64) words of adjacency/valid bitmask
#define NPAD_ 3648    // NW_*64
#define RPW_ 4        // rows per wave (k_adj)
#define RPB_ 16       // rows per block (k_adj, 4 waves)
#define TPI_ 1596     // transpose tiles per image: 57*56/2
#define HW0_ 1856     // j-half 0: words 0..28  (29 words)
#define HW1_ 1792     // j-half 1: words 29..56 (28 words)
#define CH_ 64        // greedy chunk size (candidates per resolution round)
#define NT_ 512       // threads in nms kernel
#define NWV_ 8        // waves in nms kernel
#define RPWG_ 8       // rows per wave in greedy phases (CH_/NWV_)

// ---------------------------------------------------------------------------
// K1: adjacency bitmask, UPPER-TRIANGLE only (words >= block's first word
// w0), LDS-staged j-range (proven R2/R4 structure; best-measured pipeline).
// IoU exactly symmetric (fmin/fmax/add/mul commutative) -> bit(i,j)==
// bit(j,i); k_tr mirrors the lower words.
// Exact division-free IoU: round_f32(inter/denom) >= 0.4f  <=>
// inter > (0.4f - 2^-26)*denom in f64 (26x24-bit product exact; midpoint
// ties round-to-even below 0.4f -> false, matching strict '>'; denom==0 =>
// inter==0 => false = reference NaN>=0.4). Diagonal cleared post-hoc.
// ---------------------------------------------------------------------------
__global__ __launch_bounds__(256, 4) void k_adj(const float* __restrict__ boxes,
                                                u64* __restrict__ adj) {
#pragma clang fp contract(off)
    __shared__ float4 sbox[HW0_];
    const int tid  = threadIdx.x;
    const int lane = tid & 63;
    const int wv   = tid >> 6;
    const int g    = blockIdx.x;                 // 0 .. B*N/16-1
    const int b    = g / (N_ / RPB_);
    const int rg   = g % (N_ / RPB_);
    const int r0   = rg * RPB_ + wv * RPW_;
    const int w0   = rg >> 2;                    // first word (block-uniform)
    const size_t bN = (size_t)b * N_;

    float4 bi[RPW_];
    float  ai[RPW_];
#pragma unroll
    for (int r = 0; r < RPW_; ++r) {
        const float4 bx = reinterpret_cast<const float4*>(boxes)[bN + r0 + r];
        const float x1 = bx.x - bx.z * 0.5f;   // reference op order
        const float y1 = bx.y - bx.w * 0.5f;
        const float x2 = x1 + bx.z;
        const float y2 = y1 + bx.w;
        bi[r] = make_float4(x1, y1, x2, y2);
        ai[r] = (x2 - x1) * (y2 - y1);
    }
    const double MID = (double)0.4f - 0x1p-26;   // exact

    u64 row[RPW_];
#pragma unroll
    for (int r = 0; r < RPW_; ++r) row[r] = 0ull;

    int jbase = 0;
    for (int h = 0; h < 2; ++h) {
        const int cnt  = h ? HW1_ : HW0_;
        const int wlo  = jbase >> 6;
        const int wcnt = cnt >> 6;
        if (w0 < wlo + wcnt) {                   // block-uniform skip
            const int tw0 = max(w0 - wlo, 0);
            const int jj0 = tw0 << 6;
            __syncthreads();
            for (int jj = jj0 + tid; jj < cnt; jj += 256) {
                const int j = jbase + jj;
                float x1 = 0.f, y1 = 0.f, x2 = 0.f, y2 = 0.f;
                if (j < N_) {
                    const float4 bx = reinterpret_cast<const float4*>(boxes)[bN + j];
                    x1 = bx.x - bx.z * 0.5f;
                    y1 = bx.y - bx.w * 0.5f;
                    x2 = x1 + bx.z;
                    y2 = y1 + bx.w;
                }
                sbox[jj] = make_float4(x1, y1, x2, y2);
            }
            __syncthreads();

            for (int tw = tw0; tw < wcnt; ++tw) {
                const int tglob = wlo + tw;
                const float4 bj = sbox[tw * 64 + lane];
                const float ajr = (bj.z - bj.x) * (bj.w - bj.y);
#pragma unroll
                for (int r = 0; r < RPW_; ++r) {
                    const float ltx = fmaxf(bi[r].x, bj.x);
                    const float lty = fmaxf(bi[r].y, bj.y);
                    const float rbx = fminf(bi[r].z, bj.z);
                    const float rby = fminf(bi[r].w, bj.w);
                    const float whx = fmaxf(rbx - ltx, 0.0f);
                    const float why = fmaxf(rby - lty, 0.0f);
                    const float inter = whx * why;
                    const float denom = (ai[r] + ajr) - inter;
                    const int pred = ((double)inter > MID * (double)denom);
                    const u64 m = __ballot(pred);
                    if (lane == tglob) row[r] = m;
                }
            }
        }
        jbase += cnt;
    }

#pragma unroll
    for (int r = 0; r < RPW_; ++r)
        if (lane == w0) row[r] &= ~(1ull << ((r0 + r) & 63));
#pragma unroll
    for (int r = 0; r < RPW_; ++r)
        if (lane >= w0 && lane < NW_)
            adj[(bN + r0 + r) * (size_t)NW_ + lane] = row[r];
}

// ---------------------------------------------------------------------------
// K1t: mirror the lower triangle (6-step shfl_xor block-swap bit-transpose,
// one wave per 64x64 tile wi>wj). Block 0 also zeroes candidate counters.
// ---------------------------------------------------------------------------
__global__ __launch_bounds__(256) void k_tr(u64* __restrict__ adj,
                                            u32* __restrict__ cnt) {
    if (blockIdx.x == 0) {
        for (int x = threadIdx.x; x < B_ * C_ * 16; x += 256) cnt[x] = 0;
    }
    const int lane = threadIdx.x & 63;
    const int wv   = threadIdx.x >> 6;
    const int p    = blockIdx.x * 4 + wv;        // 0 .. B*TPI-1 (exact)
    const int b    = p / TPI_;
    const int p2   = p % TPI_;
    int wi = (int)((1.0f + sqrtf((float)(8 * p2 + 1))) * 0.5f);
    while (wi * (wi - 1) / 2 > p2) --wi;
    while ((wi + 1) * wi / 2 <= p2) ++wi;
    const int wj = p2 - wi * (wi - 1) / 2;       // wj < wi
    const size_t bN = (size_t)b * N_;

    u64 x = adj[(bN + wj * 64 + lane) * (size_t)NW_ + wi];

    const u64 M[6] = {0x00000000FFFFFFFFull, 0x0000FFFF0000FFFFull,
                      0x00FF00FF00FF00FFull, 0x0F0F0F0F0F0F0F0Full,
                      0x3333333333333333ull, 0x5555555555555555ull};
#pragma unroll
    for (int si = 0; si < 6; ++si) {
        const int s = 32 >> si;
        const u64 m = M[si];
        const u64 t = __shfl_xor(x, s);
        x = ((lane & s) == 0) ? ((x & m) | ((t & m) << s))
                              : ((x & ~m) | ((t & ~m) >> s));
    }
    const int rowi = wi * 64 + lane;
    if (rowi < N_)
        adj[(bN + rowi) * (size_t)NW_ + wj] = x;
}

// ---------------------------------------------------------------------------
// K1b: acon + candidate emission (proven R4/R5 code). One wave per row;
// sparse con gather + 6-step shuffle max-reduce; lane 0 evaluates
// valid0 = (p>=conf_c) && (p>=fmax(adj_con,con_c)) (exact: p>=a && p>=b <=>
// p>=fmax(a,b), non-NaN; adj_con init 0 matches where(adj,con,0), subsumes
// p>=0) and emits sort key (~pk)<<32|i via atomicAdd. Arrival order
// nondeterministic; keys unique -> sort deterministic.
// ---------------------------------------------------------------------------
__global__ __launch_bounds__(256) void k_acon(const u64* __restrict__ adj,
                                              const float* __restrict__ con,
                                              const float* __restrict__ pro,
                                              const float* __restrict__ conf,
                                              u64* __restrict__ cand,
                                              u32* __restrict__ cnt) {
    const int tid  = threadIdx.x;
    const int lane = tid & 63;
    const int wv   = tid >> 6;
    const int g    = blockIdx.x;                 // 0 .. B*N/4-1
    const int b    = g / (N_ / 4);
    const int i    = (g % (N_ / 4)) * 4 + wv;
    const size_t bN = (size_t)b * N_;

    u64 w = (lane < NW_) ? adj[(bN + i) * (size_t)NW_ + lane] : 0ull;

    float cm[C_];
#pragma unroll
    for (int k = 0; k < C_; ++k) cm[k] = 0.0f;

    while (w) {
        const int bit = __builtin_ctzll(w); w &= w - 1;
        const int j   = lane * 64 + bit;
        const float4* cp = reinterpret_cast<const float4*>(con + (bN + j) * C_);
        const float4 c0 = cp[0], c1 = cp[1], c2 = cp[2], c3 = cp[3];
        cm[0]  = fmaxf(cm[0],  c0.x); cm[1]  = fmaxf(cm[1],  c0.y);
        cm[2]  = fmaxf(cm[2],  c0.z); cm[3]  = fmaxf(cm[3],  c0.w);
        cm[4]  = fmaxf(cm[4],  c1.x); cm[5]  = fmaxf(cm[5],  c1.y);
        cm[6]  = fmaxf(cm[6],  c1.z); cm[7]  = fmaxf(cm[7],  c1.w);
        cm[8]  = fmaxf(cm[8],  c2.x); cm[9]  = fmaxf(cm[9],  c2.y);
        cm[10] = fmaxf(cm[10], c2.z); cm[11] = fmaxf(cm[11], c2.w);
        cm[12] = fmaxf(cm[12], c3.x); cm[13] = fmaxf(cm[13], c3.y);
        cm[14] = fmaxf(cm[14], c3.z); cm[15] = fmaxf(cm[15], c3.w);
    }

#pragma unroll
    for (int off = 1; off < 64; off <<= 1) {
#pragma unroll
        for (int k = 0; k < C_; ++k) cm[k] = fmaxf(cm[k], __shfl_xor(cm[k], off));
    }
    if (lane == 0) {
        const float4* cp = reinterpret_cast<const float4*>(con + (bN + i) * C_);
        const float4 c0 = cp[0], c1 = cp[1], c2 = cp[2], c3 = cp[3];
        const float4* pp = reinterpret_cast<const float4*>(pro + (bN + i) * C_);
        const float4 p0 = pp[0], p1 = pp[1], p2 = pp[2], p3 = pp[3];
        const float4* fp = reinterpret_cast<const float4*>(conf);
        const float4 f0 = fp[0], f1 = fp[1], f2 = fp[2], f3 = fp[3];
        const float th[C_] = {
            fmaxf(cm[0],  c0.x), fmaxf(cm[1],  c0.y),
            fmaxf(cm[2],  c0.z), fmaxf(cm[3],  c0.w),
            fmaxf(cm[4],  c1.x), fmaxf(cm[5],  c1.y),
            fmaxf(cm[6],  c1.z), fmaxf(cm[7],  c1.w),
            fmaxf(cm[8],  c2.x), fmaxf(cm[9],  c2.y),
            fmaxf(cm[10], c2.z), fmaxf(cm[11], c2.w),
            fmaxf(cm[12], c3.x), fmaxf(cm[13], c3.y),
            fmaxf(cm[14], c3.z), fmaxf(cm[15], c3.w)};
        const float pr[C_] = {p0.x, p0.y, p0.z, p0.w, p1.x, p1.y, p1.z, p1.w,
                              p2.x, p2.y, p2.z, p2.w, p3.x, p3.y, p3.z, p3.w};
        const float cf[C_] = {f0.x, f0.y, f0.z, f0.w, f1.x, f1.y, f1.z, f1.w,
                              f2.x, f2.y, f2.z, f2.w, f3.x, f3.y, f3.z, f3.w};
#pragma unroll
        for (int k = 0; k < C_; ++k) {
            if (pr[k] >= cf[k] && pr[k] >= th[k]) {
                const u32 pb = __float_as_uint(pr[k]);
                const u32 pk = pb ^ ((pb >> 31) ? 0xFFFFFFFFu : 0x80000000u);
                const u32 pos = atomicAdd(&cnt[(b * C_ + k) * 16], 1u);
                cand[(size_t)(b * C_ + k) * N_ + pos] =
                    (((u64)(~pk)) << 32) | (u32)i;
            }
        }
    }
}

// ---------------------------------------------------------------------------
// K2 (k_nms_core): verbatim R5 sort + chunked greedy, but the 5.4 MB
// full-slice output is REMOVED — it ends by dumping the survivor list
// (idx + score + count) to workspace. Rationale: R5's hbm_bytes/dur == 254
// GB/s and R8's == 92 GB/s suggest these 64-block kernels are throttled by
// their memory phases at low concurrency; the output slice is the largest
// removable piece and k_out rewrites it at 450-block concurrency.
// Exactness unchanged: parallel peeling == sequential greedy (R6-proven);
// survivor order == greedy order == reference order.
// ---------------------------------------------------------------------------
union OvT {
    u64 keys[NPAD_];
    u64 srows[2][CH_][NW_];
};

__global__ __launch_bounds__(NT_) void k_nms_core(const u64* __restrict__ cand,
                                                  const u32* __restrict__ cnt,
                                                  const u64* __restrict__ adj,
                                                  u32* __restrict__ scnt,
                                                  u32* __restrict__ sl,
                                                  float* __restrict__ sf) {
#pragma clang fp contract(off)
    __shared__ OvT ov;
    __shared__ u32 sidx[NPAD_];
    __shared__ float sscore[NPAD_];
    __shared__ u64 sintra[CH_];
    __shared__ u64 vmask[NW_];
    __shared__ u64 s_accept;
    __shared__ u32 slist[NPAD_];
    __shared__ float slistf[NPAD_];
    __shared__ u32 s_S;
    const int tid  = threadIdx.x;
    const int lane = tid & 63;
    const int wv   = tid >> 6;
    const int bc   = blockIdx.x;
    const int b    = bc / C_;
    const size_t bN = (size_t)b * N_;

    const int T  = (int)cnt[bc * 16];
    const int TW = (T + 63) >> 6;
    for (int x = tid; x < TW * 64; x += NT_)
        ov.keys[x] = (x < T) ? cand[(size_t)bc * N_ + x] : ~0ull;
    if (tid < NW_) vmask[tid] = 0ull;
    __syncthreads();

    // --- rank sort via readlane broadcasts (R5-proven) ---
    for (int xp = 0; xp * NT_ < T; ++xp) {
        const int x  = xp * NT_ + tid;
        const u64 kx = (x < T) ? ov.keys[x] : ~0ull;
        u32 rank = 0;
        for (int yb = 0; yb < TW; ++yb) {
            const u64 ky = ov.keys[yb * 64 + lane];
            const u32 kyl = (u32)ky, kyh = (u32)(ky >> 32);
#pragma unroll
            for (int l = 0; l < 64; ++l) {
                const u64 kb =
                    ((u64)(u32)__builtin_amdgcn_readlane((int)kyh, l) << 32)
                  |  (u64)(u32)__builtin_amdgcn_readlane((int)kyl, l);
                rank += (kb < kx) ? 1u : 0u;
            }
        }
        if (x < T) {
            const u32 i = (u32)(kx & 0xFFFFFFFFull);
            sidx[rank] = i;
            const u32 pk = ~((u32)(kx >> 32));
            const u32 pb = (pk & 0x80000000u) ? (pk ^ 0x80000000u) : ~pk;
            sscore[rank] = __uint_as_float(pb);
            atomicOr(&vmask[i >> 6], 1ull << (i & 63));
        }
    }
    __syncthreads();                     // keys dead; srows may overlay now

    // --- chunk-parallel greedy (verbatim R5) ---
#pragma unroll
    for (int rr = 0; rr < RPWG_; ++rr) {
        const int r = wv * RPWG_ + rr;
        const u32 idx = (r < T) ? sidx[r] : 0u;
        if (lane < NW_)
            ov.srows[0][r][lane] = adj[(bN + idx) * (size_t)NW_ + lane];
    }
    __syncthreads();

    u32 S = 0;                           // meaningful in wave 0
    const int NCH = (T + CH_ - 1) / CH_;
    for (int ch = 0; ch < NCH; ++ch) {
        const int cur = ch & 1, nxt = cur ^ 1;
        const int c0 = ch * CH_;
        const int cn = min(CH_, T - c0);
        const int havenext = (ch + 1 < NCH);

        u64 pre[RPWG_];
#pragma unroll
        for (int rr = 0; rr < RPWG_; ++rr) {
            const int r = wv * RPWG_ + rr;
            const int q = c0 + CH_ + r;
            const u32 idxn = (havenext && q < T) ? sidx[q] : 0u;
            pre[rr] = (havenext && lane < NW_)
                        ? adj[(bN + idxn) * (size_t)NW_ + lane] : 0ull;
        }
#pragma unroll
        for (int rr = 0; rr < RPWG_; ++rr) {
            const int r = wv * RPWG_ + rr;
            const u32 idxr = (c0 + r < T) ? sidx[c0 + r] : 0u;
            const u64 rj = ov.srows[cur][lane][idxr >> 6];
            const u64 ib = __ballot((lane < cn) && ((rj >> (idxr & 63)) & 1ull));
            if (lane == 0) sintra[r] = ib;
        }
        __syncthreads();

        if (wv == 0) {
            const u32 idxme = (c0 + lane < T) ? sidx[c0 + lane] : 0u;
            const u64 vm = vmask[idxme >> 6];
            u64 cv = __ballot((lane < cn) && ((vm >> (idxme & 63)) & 1ull));
            const u64 iv = sintra[lane];
            const u64 below = (1ull << lane) - 1ull;
            u64 accept = 0ull;
            while (cv) {
                const int ok = ((cv >> lane) & 1ull) &&
                               ((iv & below & cv) == 0ull);
                const u64 ar = __ballot(ok);
                u64 sup = ok ? iv : 0ull;
#pragma unroll
                for (int off = 1; off < 64; off <<= 1)
                    sup |= __shfl_xor(sup, off);
                accept |= ar;
                cv &= ~(ar | sup);
            }
            if (lane == 0) s_accept = accept;
            if ((accept >> lane) & 1ull) {
                const u32 pos = S + (u32)__popcll(accept & below);
                slist[pos]  = idxme;
                slistf[pos] = sscore[c0 + lane];
            }
            S += (u32)__popcll(accept);
        }
        __syncthreads();

        const u64 ac = s_accept;
        u64 acc = 0ull;
#pragma unroll
        for (int rr = 0; rr < RPWG_; ++rr) {
            const int r = wv * RPWG_ + rr;
            if ((ac >> r) & 1ull)
                acc |= ov.srows[cur][r][min(lane, NW_ - 1)];
        }
        if (lane < NW_ && acc)
            atomicAnd(&vmask[lane], ~acc);
        if (havenext) {
#pragma unroll
            for (int rr = 0; rr < RPWG_; ++rr) {
                const int r = wv * RPWG_ + rr;
                if (lane < NW_) ov.srows[nxt][r][lane] = pre[rr];
            }
        }
        __syncthreads();
    }
    if (wv == 0 && lane == 0) { s_S = S; scnt[bc] = S; }
    __syncthreads();

    // --- dump survivor list to workspace (small, coalesced) ---
    const int Sf = (int)s_S;
    for (int r = tid; r < Sf; r += NT_) {
        sl[(size_t)bc * N_ + r] = slist[r];
        sf[(size_t)bc * N_ + r] = slistf[r];
    }
}

// ---------------------------------------------------------------------------
// K3 (k_out): full-slice output at FULL-GPU concurrency (450 blocks). One
// thread per (bc, r): survivors get scaled xyxy + score + mask=1; the rest
// exact zeros (absorbs the memset). Survivor order from k_nms_core ==
// reference output order.
// ---------------------------------------------------------------------------
__global__ __launch_bounds__(512) void k_out(const u32* __restrict__ scnt,
                                             const u32* __restrict__ sl,
                                             const float* __restrict__ sf,
                                             const float* __restrict__ boxes,
                                             const float* __restrict__ scales,
                                             float* __restrict__ out) {
#pragma clang fp contract(off)
    const int x = blockIdx.x * 512 + threadIdx.x;    // 0 .. B*C*N-1
    if (x >= B_ * C_ * N_) return;
    const int bc = x / N_;
    const int r  = x - bc * N_;
    const int b  = bc / C_;
    const int S  = (int)scnt[bc];

    float o0 = 0.f, o1 = 0.f, o2 = 0.f, o3 = 0.f, o4 = 0.f, mk = 0.f;
    if (r < S) {
        const int idx = (int)sl[(size_t)bc * N_ + r];
        const float4 bx =
            reinterpret_cast<const float4*>(boxes)[(size_t)b * N_ + idx];
        const float s = scales[b];
        const float scx = bx.x * s, scy = bx.y * s;
        const float sw  = bx.z * s, sh  = bx.w * s;
        o0 = scx - 0.5f * sw;
        o1 = scy - 0.5f * sh;
        o2 = scx + 0.5f * sw;
        o3 = scy + 0.5f * sh;
        o4 = sf[(size_t)bc * N_ + r];
        mk = 1.0f;
    }
    float* o = out + (size_t)x * 5;
    o[0] = o0; o[1] = o1; o[2] = o2; o[3] = o3; o[4] = o4;
    out[(size_t)B_ * C_ * N_ * 5 + x] = mk;
}

// ---------------------------------------------------------------------------
extern "C" void kernel_launch(void* const* d_in, const int* in_sizes, int n_in,
                              void* d_out, int out_size, void* d_ws, size_t ws_size,
                              hipStream_t stream) {
    const float* pro    = (const float*)d_in[0];   // (B,N,C)
    const float* con    = (const float*)d_in[1];   // (B,N,C)
    const float* boxes  = (const float*)d_in[2];   // (B,N,4)
    const float* scales = (const float*)d_in[3];   // (B,)
    const float* conf   = (const float*)d_in[4];   // (C,)

    char* ws = (char*)d_ws;
    u64* adj = (u64*)ws;                                   // B*N*NW u64  (6.57 MB)
    size_t off = (size_t)B_ * N_ * NW_ * sizeof(u64);
    u64* cand = (u64*)(ws + off);                          // B*C*N u64   (1.84 MB)
    off += (size_t)B_ * C_ * N_ * sizeof(u64);
    u32* cnt = (u32*)(ws + off);                           // B*C*16 u32  (4 KB)
    off += (size_t)B_ * C_ * 16 * sizeof(u32);
    u32* scnt = (u32*)(ws + off);                          // B*C u32
    off += (size_t)B_ * C_ * sizeof(u32);
    u32* sl = (u32*)(ws + off);                            // B*C*N u32   (0.92 MB)
    off += (size_t)B_ * C_ * N_ * sizeof(u32);
    float* sf = (float*)(ws + off);                        // B*C*N f32   (0.92 MB)

    k_adj     <<<B_ * N_ / RPB_, 256, 0, stream>>>(boxes, adj);
    k_tr      <<<B_ * TPI_ / 4,  256, 0, stream>>>(adj, cnt);
    k_acon    <<<B_ * N_ / 4,    256, 0, stream>>>(adj, con, pro, conf, cand, cnt);
    k_nms_core<<<B_ * C_,        NT_, 0, stream>>>(cand, cnt, adj, scnt, sl, sf);
    k_out     <<<450,            512, 0, stream>>>(scnt, sl, sf, boxes, scales,
                                                   (float*)d_out);
}

// Round 11
// 156.707 us; speedup vs baseline: 7.4732x; 1.0302x over previous
//
#include <hip/hip_runtime.h>
#include <cstdint>

typedef unsigned long long u64;
typedef unsigned int u32;

#define B_ 4
#define N_ 3600
#define C_ 16
#define NW_ 57        // ceil(N/64) words of adjacency/valid bitmask
#define NPAD_ 3648    // NW_*64
#define RPW_ 4        // rows per wave (k_adj)
#define RPB_ 16       // rows per block (k_adj, 4 waves)
#define TPI_ 1596     // transpose tiles per image: 57*56/2
#define HW0_ 1856     // j-half 0: words 0..28  (29 words)
#define HW1_ 1792     // j-half 1: words 29..56 (28 words)
#define CH_ 64        // greedy chunk size (candidates per resolution round)
#define NTC_ 1024     // threads in k_nms_core (16 waves -> 4/SIMD)
#define NWVC_ 16      // waves in k_nms_core
#define RPWGC_ 4      // rows per wave in greedy phases (CH_/NWVC_)

// ---------------------------------------------------------------------------
// K1: adjacency bitmask, UPPER-TRIANGLE only (words >= block's first word
// w0), LDS-staged j-range (proven R2/R4 structure; best-measured pipeline).
// IoU exactly symmetric (fmin/fmax/add/mul commutative) -> bit(i,j)==
// bit(j,i); k_tr mirrors the lower words.
// Exact division-free IoU: round_f32(inter/denom) >= 0.4f  <=>
// inter > (0.4f - 2^-26)*denom in f64 (26x24-bit product exact; midpoint
// ties round-to-even below 0.4f -> false, matching strict '>'; denom==0 =>
// inter==0 => false = reference NaN>=0.4). Diagonal cleared post-hoc.
// ---------------------------------------------------------------------------
__global__ __launch_bounds__(256, 4) void k_adj(const float* __restrict__ boxes,
                                                u64* __restrict__ adj) {
#pragma clang fp contract(off)
    __shared__ float4 sbox[HW0_];
    const int tid  = threadIdx.x;
    const int lane = tid & 63;
    const int wv   = tid >> 6;
    const int g    = blockIdx.x;                 // 0 .. B*N/16-1
    const int b    = g / (N_ / RPB_);
    const int rg   = g % (N_ / RPB_);
    const int r0   = rg * RPB_ + wv * RPW_;
    const int w0   = rg >> 2;                    // first word (block-uniform)
    const size_t bN = (size_t)b * N_;

    float4 bi[RPW_];
    float  ai[RPW_];
#pragma unroll
    for (int r = 0; r < RPW_; ++r) {
        const float4 bx = reinterpret_cast<const float4*>(boxes)[bN + r0 + r];
        const float x1 = bx.x - bx.z * 0.5f;   // reference op order
        const float y1 = bx.y - bx.w * 0.5f;
        const float x2 = x1 + bx.z;
        const float y2 = y1 + bx.w;
        bi[r] = make_float4(x1, y1, x2, y2);
        ai[r] = (x2 - x1) * (y2 - y1);
    }
    const double MID = (double)0.4f - 0x1p-26;   // exact

    u64 row[RPW_];
#pragma unroll
    for (int r = 0; r < RPW_; ++r) row[r] = 0ull;

    int jbase = 0;
    for (int h = 0; h < 2; ++h) {
        const int cnt  = h ? HW1_ : HW0_;
        const int wlo  = jbase >> 6;
        const int wcnt = cnt >> 6;
        if (w0 < wlo + wcnt) {                   // block-uniform skip
            const int tw0 = max(w0 - wlo, 0);
            const int jj0 = tw0 << 6;
            __syncthreads();
            for (int jj = jj0 + tid; jj < cnt; jj += 256) {
                const int j = jbase + jj;
                float x1 = 0.f, y1 = 0.f, x2 = 0.f, y2 = 0.f;
                if (j < N_) {
                    const float4 bx = reinterpret_cast<const float4*>(boxes)[bN + j];
                    x1 = bx.x - bx.z * 0.5f;
                    y1 = bx.y - bx.w * 0.5f;
                    x2 = x1 + bx.z;
                    y2 = y1 + bx.w;
                }
                sbox[jj] = make_float4(x1, y1, x2, y2);
            }
            __syncthreads();

            for (int tw = tw0; tw < wcnt; ++tw) {
                const int tglob = wlo + tw;
                const float4 bj = sbox[tw * 64 + lane];
                const float ajr = (bj.z - bj.x) * (bj.w - bj.y);
#pragma unroll
                for (int r = 0; r < RPW_; ++r) {
                    const float ltx = fmaxf(bi[r].x, bj.x);
                    const float lty = fmaxf(bi[r].y, bj.y);
                    const float rbx = fminf(bi[r].z, bj.z);
                    const float rby = fminf(bi[r].w, bj.w);
                    const float whx = fmaxf(rbx - ltx, 0.0f);
                    const float why = fmaxf(rby - lty, 0.0f);
                    const float inter = whx * why;
                    const float denom = (ai[r] + ajr) - inter;
                    const int pred = ((double)inter > MID * (double)denom);
                    const u64 m = __ballot(pred);
                    if (lane == tglob) row[r] = m;
                }
            }
        }
        jbase += cnt;
    }

#pragma unroll
    for (int r = 0; r < RPW_; ++r)
        if (lane == w0) row[r] &= ~(1ull << ((r0 + r) & 63));
#pragma unroll
    for (int r = 0; r < RPW_; ++r)
        if (lane >= w0 && lane < NW_)
            adj[(bN + r0 + r) * (size_t)NW_ + lane] = row[r];
}

// ---------------------------------------------------------------------------
// K1t: mirror the lower triangle (6-step shfl_xor block-swap bit-transpose,
// one wave per 64x64 tile wi>wj). Block 0 also zeroes candidate counters.
// ---------------------------------------------------------------------------
__global__ __launch_bounds__(256) void k_tr(u64* __restrict__ adj,
                                            u32* __restrict__ cnt) {
    if (blockIdx.x == 0) {
        for (int x = threadIdx.x; x < B_ * C_ * 16; x += 256) cnt[x] = 0;
    }
    const int lane = threadIdx.x & 63;
    const int wv   = threadIdx.x >> 6;
    const int p    = blockIdx.x * 4 + wv;        // 0 .. B*TPI-1 (exact)
    const int b    = p / TPI_;
    const int p2   = p % TPI_;
    int wi = (int)((1.0f + sqrtf((float)(8 * p2 + 1))) * 0.5f);
    while (wi * (wi - 1) / 2 > p2) --wi;
    while ((wi + 1) * wi / 2 <= p2) ++wi;
    const int wj = p2 - wi * (wi - 1) / 2;       // wj < wi
    const size_t bN = (size_t)b * N_;

    u64 x = adj[(bN + wj * 64 + lane) * (size_t)NW_ + wi];

    const u64 M[6] = {0x00000000FFFFFFFFull, 0x0000FFFF0000FFFFull,
                      0x00FF00FF00FF00FFull, 0x0F0F0F0F0F0F0F0Full,
                      0x3333333333333333ull, 0x5555555555555555ull};
#pragma unroll
    for (int si = 0; si < 6; ++si) {
        const int s = 32 >> si;
        const u64 m = M[si];
        const u64 t = __shfl_xor(x, s);
        x = ((lane & s) == 0) ? ((x & m) | ((t & m) << s))
                              : ((x & ~m) | ((t & ~m) >> s));
    }
    const int rowi = wi * 64 + lane;
    if (rowi < N_)
        adj[(bN + rowi) * (size_t)NW_ + wj] = x;
}

// ---------------------------------------------------------------------------
// K1b: acon + candidate emission (proven R4/R5 code). One wave per row;
// sparse con gather + 6-step shuffle max-reduce; lane 0 evaluates
// valid0 = (p>=conf_c) && (p>=fmax(adj_con,con_c)) (exact: p>=a && p>=b <=>
// p>=fmax(a,b), non-NaN; adj_con init 0 matches where(adj,con,0), subsumes
// p>=0) and emits sort key (~pk)<<32|i via atomicAdd. Arrival order
// nondeterministic; keys unique -> sort deterministic.
// ---------------------------------------------------------------------------
__global__ __launch_bounds__(256) void k_acon(const u64* __restrict__ adj,
                                              const float* __restrict__ con,
                                              const float* __restrict__ pro,
                                              const float* __restrict__ conf,
                                              u64* __restrict__ cand,
                                              u32* __restrict__ cnt) {
    const int tid  = threadIdx.x;
    const int lane = tid & 63;
    const int wv   = tid >> 6;
    const int g    = blockIdx.x;                 // 0 .. B*N/4-1
    const int b    = g / (N_ / 4);
    const int i    = (g % (N_ / 4)) * 4 + wv;
    const size_t bN = (size_t)b * N_;

    u64 w = (lane < NW_) ? adj[(bN + i) * (size_t)NW_ + lane] : 0ull;

    float cm[C_];
#pragma unroll
    for (int k = 0; k < C_; ++k) cm[k] = 0.0f;

    while (w) {
        const int bit = __builtin_ctzll(w); w &= w - 1;
        const int j   = lane * 64 + bit;
        const float4* cp = reinterpret_cast<const float4*>(con + (bN + j) * C_);
        const float4 c0 = cp[0], c1 = cp[1], c2 = cp[2], c3 = cp[3];
        cm[0]  = fmaxf(cm[0],  c0.x); cm[1]  = fmaxf(cm[1],  c0.y);
        cm[2]  = fmaxf(cm[2],  c0.z); cm[3]  = fmaxf(cm[3],  c0.w);
        cm[4]  = fmaxf(cm[4],  c1.x); cm[5]  = fmaxf(cm[5],  c1.y);
        cm[6]  = fmaxf(cm[6],  c1.z); cm[7]  = fmaxf(cm[7],  c1.w);
        cm[8]  = fmaxf(cm[8],  c2.x); cm[9]  = fmaxf(cm[9],  c2.y);
        cm[10] = fmaxf(cm[10], c2.z); cm[11] = fmaxf(cm[11], c2.w);
        cm[12] = fmaxf(cm[12], c3.x); cm[13] = fmaxf(cm[13], c3.y);
        cm[14] = fmaxf(cm[14], c3.z); cm[15] = fmaxf(cm[15], c3.w);
    }

#pragma unroll
    for (int off = 1; off < 64; off <<= 1) {
#pragma unroll
        for (int k = 0; k < C_; ++k) cm[k] = fmaxf(cm[k], __shfl_xor(cm[k], off));
    }
    if (lane == 0) {
        const float4* cp = reinterpret_cast<const float4*>(con + (bN + i) * C_);
        const float4 c0 = cp[0], c1 = cp[1], c2 = cp[2], c3 = cp[3];
        const float4* pp = reinterpret_cast<const float4*>(pro + (bN + i) * C_);
        const float4 p0 = pp[0], p1 = pp[1], p2 = pp[2], p3 = pp[3];
        const float4* fp = reinterpret_cast<const float4*>(conf);
        const float4 f0 = fp[0], f1 = fp[1], f2 = fp[2], f3 = fp[3];
        const float th[C_] = {
            fmaxf(cm[0],  c0.x), fmaxf(cm[1],  c0.y),
            fmaxf(cm[2],  c0.z), fmaxf(cm[3],  c0.w),
            fmaxf(cm[4],  c1.x), fmaxf(cm[5],  c1.y),
            fmaxf(cm[6],  c1.z), fmaxf(cm[7],  c1.w),
            fmaxf(cm[8],  c2.x), fmaxf(cm[9],  c2.y),
            fmaxf(cm[10], c2.z), fmaxf(cm[11], c2.w),
            fmaxf(cm[12], c3.x), fmaxf(cm[13], c3.y),
            fmaxf(cm[14], c3.z), fmaxf(cm[15], c3.w)};
        const float pr[C_] = {p0.x, p0.y, p0.z, p0.w, p1.x, p1.y, p1.z, p1.w,
                              p2.x, p2.y, p2.z, p2.w, p3.x, p3.y, p3.z, p3.w};
        const float cf[C_] = {f0.x, f0.y, f0.z, f0.w, f1.x, f1.y, f1.z, f1.w,
                              f2.x, f2.y, f2.z, f2.w, f3.x, f3.y, f3.z, f3.w};
#pragma unroll
        for (int k = 0; k < C_; ++k) {
            if (pr[k] >= cf[k] && pr[k] >= th[k]) {
                const u32 pb = __float_as_uint(pr[k]);
                const u32 pk = pb ^ ((pb >> 31) ? 0xFFFFFFFFu : 0x80000000u);
                const u32 pos = atomicAdd(&cnt[(b * C_ + k) * 16], 1u);
                cand[(size_t)(b * C_ + k) * N_ + pos] =
                    (((u64)(~pk)) << 32) | (u32)i;
            }
        }
    }
}

// ---------------------------------------------------------------------------
// K2 (k_nms_core): R10-verified sort + chunked greedy + survivor-list dump,
// widened to 1024 threads (16 waves, 4 rows/wave in phases A/C). Rationale:
// phase A prefetches 64 scattered 456-B adj rows (~448 cache lines) per
// chunk with only 8 waves to cover L2 latency; 16 waves double outstanding
// loads and halve per-wave A/C work. Phase B (wave-0 peel) and all logic
// unchanged. LDS 117.7 KB -> still 1 block/CU; 16 waves = 4/SIMD.
// Exactness: parallel peeling == sequential greedy (R6-proven); survivor
// order == greedy order == reference order.
// ---------------------------------------------------------------------------
union OvT {
    u64 keys[NPAD_];
    u64 srows[2][CH_][NW_];
};

__global__ __launch_bounds__(NTC_) void k_nms_core(const u64* __restrict__ cand,
                                                   const u32* __restrict__ cnt,
                                                   const u64* __restrict__ adj,
                                                   u32* __restrict__ scnt,
                                                   u32* __restrict__ sl,
                                                   float* __restrict__ sf) {
#pragma clang fp contract(off)
    __shared__ OvT ov;
    __shared__ u32 sidx[NPAD_];
    __shared__ float sscore[NPAD_];
    __shared__ u64 sintra[CH_];
    __shared__ u64 vmask[NW_];
    __shared__ u64 s_accept;
    __shared__ u32 slist[NPAD_];
    __shared__ float slistf[NPAD_];
    __shared__ u32 s_S;
    const int tid  = threadIdx.x;
    const int lane = tid & 63;
    const int wv   = tid >> 6;
    const int bc   = blockIdx.x;
    const int b    = bc / C_;
    const size_t bN = (size_t)b * N_;

    const int T  = (int)cnt[bc * 16];
    const int TW = (T + 63) >> 6;
    for (int x = tid; x < TW * 64; x += NTC_)
        ov.keys[x] = (x < T) ? cand[(size_t)bc * N_ + x] : ~0ull;
    if (tid < NW_) vmask[tid] = 0ull;
    __syncthreads();

    // --- rank sort via readlane broadcasts (R5-proven) ---
    for (int xp = 0; xp * NTC_ < T; ++xp) {
        const int x  = xp * NTC_ + tid;
        const u64 kx = (x < T) ? ov.keys[x] : ~0ull;
        u32 rank = 0;
        if (x < TW * 64) {                       // gate idle upper waves
            for (int yb = 0; yb < TW; ++yb) {
                const u64 ky = ov.keys[yb * 64 + lane];
                const u32 kyl = (u32)ky, kyh = (u32)(ky >> 32);
#pragma unroll
                for (int l = 0; l < 64; ++l) {
                    const u64 kb =
                        ((u64)(u32)__builtin_amdgcn_readlane((int)kyh, l) << 32)
                      |  (u64)(u32)__builtin_amdgcn_readlane((int)kyl, l);
                    rank += (kb < kx) ? 1u : 0u;
                }
            }
        }
        if (x < T) {
            const u32 i = (u32)(kx & 0xFFFFFFFFull);
            sidx[rank] = i;
            const u32 pk = ~((u32)(kx >> 32));
            const u32 pb = (pk & 0x80000000u) ? (pk ^ 0x80000000u) : ~pk;
            sscore[rank] = __uint_as_float(pb);
            atomicOr(&vmask[i >> 6], 1ull << (i & 63));
        }
    }
    __syncthreads();                     // keys dead; srows may overlay now

    // --- chunk-parallel greedy ---
#pragma unroll
    for (int rr = 0; rr < RPWGC_; ++rr) {
        const int r = wv * RPWGC_ + rr;
        const u32 idx = (r < T) ? sidx[r] : 0u;
        if (lane < NW_)
            ov.srows[0][r][lane] = adj[(bN + idx) * (size_t)NW_ + lane];
    }
    __syncthreads();

    u32 S = 0;                           // meaningful in wave 0
    const int NCH = (T + CH_ - 1) / CH_;
    for (int ch = 0; ch < NCH; ++ch) {
        const int cur = ch & 1, nxt = cur ^ 1;
        const int c0 = ch * CH_;
        const int cn = min(CH_, T - c0);
        const int havenext = (ch + 1 < NCH);

        u64 pre[RPWGC_];
#pragma unroll
        for (int rr = 0; rr < RPWGC_; ++rr) {
            const int r = wv * RPWGC_ + rr;
            const int q = c0 + CH_ + r;
            const u32 idxn = (havenext && q < T) ? sidx[q] : 0u;
            pre[rr] = (havenext && lane < NW_)
                        ? adj[(bN + idxn) * (size_t)NW_ + lane] : 0ull;
        }
#pragma unroll
        for (int rr = 0; rr < RPWGC_; ++rr) {
            const int r = wv * RPWGC_ + rr;
            const u32 idxr = (c0 + r < T) ? sidx[c0 + r] : 0u;
            const u64 rj = ov.srows[cur][lane][idxr >> 6];
            const u64 ib = __ballot((lane < cn) && ((rj >> (idxr & 63)) & 1ull));
            if (lane == 0) sintra[r] = ib;
        }
        __syncthreads();

        if (wv == 0) {
            const u32 idxme = (c0 + lane < T) ? sidx[c0 + lane] : 0u;
            const u64 vm = vmask[idxme >> 6];
            u64 cv = __ballot((lane < cn) && ((vm >> (idxme & 63)) & 1ull));
            const u64 iv = sintra[lane];
            const u64 below = (1ull << lane) - 1ull;
            u64 accept = 0ull;
            while (cv) {
                const int ok = ((cv >> lane) & 1ull) &&
                               ((iv & below & cv) == 0ull);
                const u64 ar = __ballot(ok);
                u64 sup = ok ? iv : 0ull;
#pragma unroll
                for (int off = 1; off < 64; off <<= 1)
                    sup |= __shfl_xor(sup, off);
                accept |= ar;
                cv &= ~(ar | sup);
            }
            if (lane == 0) s_accept = accept;
            if ((accept >> lane) & 1ull) {
                const u32 pos = S + (u32)__popcll(accept & below);
                slist[pos]  = idxme;
                slistf[pos] = sscore[c0 + lane];
            }
            S += (u32)__popcll(accept);
        }
        __syncthreads();

        const u64 ac = s_accept;
        u64 acc = 0ull;
#pragma unroll
        for (int rr = 0; rr < RPWGC_; ++rr) {
            const int r = wv * RPWGC_ + rr;
            if ((ac >> r) & 1ull)
                acc |= ov.srows[cur][r][min(lane, NW_ - 1)];
        }
        if (lane < NW_ && acc)
            atomicAnd(&vmask[lane], ~acc);
        if (havenext) {
#pragma unroll
            for (int rr = 0; rr < RPWGC_; ++rr) {
                const int r = wv * RPWGC_ + rr;
                if (lane < NW_) ov.srows[nxt][r][lane] = pre[rr];
            }
        }
        __syncthreads();
    }
    if (wv == 0 && lane == 0) { s_S = S; scnt[bc] = S; }
    __syncthreads();

    // --- dump survivor list to workspace (small, coalesced) ---
    const int Sf = (int)s_S;
    for (int r = tid; r < Sf; r += NTC_) {
        sl[(size_t)bc * N_ + r] = slist[r];
        sf[(size_t)bc * N_ + r] = slistf[r];
    }
}

// ---------------------------------------------------------------------------
// K3 (k_out): full-slice output at FULL-GPU concurrency (450 blocks). One
// thread per (bc, r): survivors get scaled xyxy + score + mask=1; the rest
// exact zeros (absorbs the memset). Survivor order from k_nms_core ==
// reference output order.
// ---------------------------------------------------------------------------
__global__ __launch_bounds__(512) void k_out(const u32* __restrict__ scnt,
                                             const u32* __restrict__ sl,
                                             const float* __restrict__ sf,
                                             const float* __restrict__ boxes,
                                             const float* __restrict__ scales,
                                             float* __restrict__ out) {
#pragma clang fp contract(off)
    const int x = blockIdx.x * 512 + threadIdx.x;    // 0 .. B*C*N-1
    if (x >= B_ * C_ * N_) return;
    const int bc = x / N_;
    const int r  = x - bc * N_;
    const int b  = bc / C_;
    const int S  = (int)scnt[bc];

    float o0 = 0.f, o1 = 0.f, o2 = 0.f, o3 = 0.f, o4 = 0.f, mk = 0.f;
    if (r < S) {
        const int idx = (int)sl[(size_t)bc * N_ + r];
        const float4 bx =
            reinterpret_cast<const float4*>(boxes)[(size_t)b * N_ + idx];
        const float s = scales[b];
        const float scx = bx.x * s, scy = bx.y * s;
        const float sw  = bx.z * s, sh  = bx.w * s;
        o0 = scx - 0.5f * sw;
        o1 = scy - 0.5f * sh;
        o2 = scx + 0.5f * sw;
        o3 = scy + 0.5f * sh;
        o4 = sf[(size_t)bc * N_ + r];
        mk = 1.0f;
    }
    float* o = out + (size_t)x * 5;
    o[0] = o0; o[1] = o1; o[2] = o2; o[3] = o3; o[4] = o4;
    out[(size_t)B_ * C_ * N_ * 5 + x] = mk;
}

// ---------------------------------------------------------------------------
extern "C" void kernel_launch(void* const* d_in, const int* in_sizes, int n_in,
                              void* d_out, int out_size, void* d_ws, size_t ws_size,
                              hipStream_t stream) {
    const float* pro    = (const float*)d_in[0];   // (B,N,C)
    const float* con    = (const float*)d_in[1];   // (B,N,C)
    const float* boxes  = (const float*)d_in[2];   // (B,N,4)
    const float* scales = (const float*)d_in[3];   // (B,)
    const float* conf   = (const float*)d_in[4];   // (C,)

    char* ws = (char*)d_ws;
    u64* adj = (u64*)ws;                                   // B*N*NW u64  (6.57 MB)
    size_t off = (size_t)B_ * N_ * NW_ * sizeof(u64);
    u64* cand = (u64*)(ws + off);                          // B*C*N u64   (1.84 MB)
    off += (size_t)B_ * C_ * N_ * sizeof(u64);
    u32* cnt = (u32*)(ws + off);                           // B*C*16 u32  (4 KB)
    off += (size_t)B_ * C_ * 16 * sizeof(u32);
    u32* scnt = (u32*)(ws + off);                          // B*C u32
    off += (size_t)B_ * C_ * sizeof(u32);
    u32* sl = (u32*)(ws + off);                            // B*C*N u32   (0.92 MB)
    off += (size_t)B_ * C_ * N_ * sizeof(u32);
    float* sf = (float*)(ws + off);                        // B*C*N f32   (0.92 MB)

    k_adj     <<<B_ * N_ / RPB_, 256, 0, stream>>>(boxes, adj);
    k_tr      <<<B_ * TPI_ / 4,  256, 0, stream>>>(adj, cnt);
    k_acon    <<<B_ * N_ / 4,    256, 0, stream>>>(adj, con, pro, conf, cand, cnt);
    k_nms_core<<<B_ * C_,        NTC_, 0, stream>>>(cand, cnt, adj, scnt, sl, sf);
    k_out     <<<450,            512, 0, stream>>>(scnt, sl, sf, boxes, scales,
                                                   (float*)d_out);
}